// Round 1
// baseline (1357.376 us; speedup 1.0000x reference)
//
#include <hip/hip_runtime.h>

#define N_B   4
#define M_PTS 8192
#define K_PTS 8192
#define CK    1024      // k-chunk staged in LDS per block
#define BM    256       // pred points per block == threads per block

// -ALPHA * log2(e): exp(-ALPHA*d) == exp2(d * C)
#define NEG_ALPHA_LOG2E (-7.21347520444481703f)
#define LN2 0.69314718055994531f

__global__ __launch_bounds__(BM) void softhaus_pairwise(
    const float* __restrict__ pred, const float* __restrict__ gt,
    float* __restrict__ row_sum, float* __restrict__ col_sum)
{
    __shared__ float2 gtile[CK];     // 8 KB
    __shared__ float  col_acc[CK];   // 4 KB

    const int mb  = blockIdx.x;   // 0..M/BM-1
    const int kb  = blockIdx.y;   // 0..K/CK-1
    const int n   = blockIdx.z;   // 0..N-1
    const int tid = threadIdx.x;

    // stage gt chunk (CK float2 = 512 float4) and zero col accumulator
    const float4* gsrc = (const float4*)(gt + ((size_t)n * K_PTS + (size_t)kb * CK) * 2);
    float4* gdst = (float4*)gtile;
    #pragma unroll
    for (int i = 0; i < CK / 2 / BM; ++i)
        gdst[tid + i * BM] = gsrc[tid + i * BM];
    #pragma unroll
    for (int i = 0; i < CK / BM; ++i)
        col_acc[tid + i * BM] = 0.0f;
    __syncthreads();

    const int m = mb * BM + tid;
    const float2 p = ((const float2*)pred)[(size_t)n * M_PTS + m];
    const float px = p.x, py = p.y;

    // skew: each lane of a wave owns a distinct k at every step -> the LDS
    // atomicAdd below never has same-address conflicts; addresses are
    // consecutive words -> conflict-free banking. Waves staggered by CK/4.
    const int lane = tid & 63;
    const int wv   = tid >> 6;
    const int koff = (lane + wv * (CK / 4)) & (CK - 1);

    float rs = 0.0f;
    for (int j0 = 0; j0 < CK; j0 += 8) {
        #pragma unroll
        for (int jj = 0; jj < 8; ++jj) {
            const int kk = (koff + j0 + jj) & (CK - 1);
            const float2 g = gtile[kk];
            const float dx = px - g.x;
            const float dy = py - g.y;
            const float s  = fmaf(dy, dy, dx * dx);
            const float d  = __builtin_amdgcn_sqrtf(s);
            const float e  = __builtin_amdgcn_exp2f(d * NEG_ALPHA_LOG2E);
            rs += e;
            atomicAdd(&col_acc[kk], e);
        }
    }
    __syncthreads();

    // row partial: one global atomic per thread (K_PTS/CK = 8-way contention)
    atomicAdd(&row_sum[(size_t)n * M_PTS + m], rs);
    // col partials: M_PTS/BM = 32-way contention
    #pragma unroll
    for (int i = 0; i < CK / BM; ++i)
        atomicAdd(&col_sum[(size_t)n * K_PTS + (size_t)kb * CK + tid + i * BM],
                  col_acc[tid + i * BM]);
}

// ws holds row_sum (N*M) followed by col_sum (N*K), contiguous.
// loss = mean(-log(row_sum)) + mean(-log(col_sum)); both parts have N*M == N*K
// elements, so a single 1/(N*M) scale applies to the grand sum of -log terms.
__global__ __launch_bounds__(256) void softhaus_finalize(
    const float* __restrict__ sums, float* __restrict__ out)
{
    const int total = N_B * M_PTS + N_B * K_PTS;
    const int idx = blockIdx.x * blockDim.x + threadIdx.x;
    const int stride = gridDim.x * blockDim.x;

    float acc = 0.0f;
    for (int i = idx; i < total; i += stride)
        acc -= __builtin_amdgcn_logf(sums[i]) * LN2;   // -log(v)

    // wave reduce (64 lanes)
    #pragma unroll
    for (int off = 32; off > 0; off >>= 1)
        acc += __shfl_down(acc, off);

    __shared__ float wsum[4];
    const int lane = threadIdx.x & 63;
    const int wv   = threadIdx.x >> 6;
    if (lane == 0) wsum[wv] = acc;
    __syncthreads();
    if (threadIdx.x == 0) {
        float b = wsum[0] + wsum[1] + wsum[2] + wsum[3];
        atomicAdd(out, b * (1.0f / (N_B * M_PTS)));
    }
}

extern "C" void kernel_launch(void* const* d_in, const int* in_sizes, int n_in,
                              void* d_out, int out_size, void* d_ws, size_t ws_size,
                              hipStream_t stream) {
    const float* pred = (const float*)d_in[0];
    const float* gt   = (const float*)d_in[1];
    float* ws = (float*)d_ws;
    float* row_sum = ws;                       // N*M floats
    float* col_sum = ws + (size_t)N_B * M_PTS; // N*K floats

    const size_t acc_bytes = (size_t)(N_B * M_PTS + N_B * K_PTS) * sizeof(float);
    hipMemsetAsync(d_ws, 0, acc_bytes, stream);
    hipMemsetAsync(d_out, 0, sizeof(float), stream);

    dim3 grid(M_PTS / BM, K_PTS / CK, N_B);   // 32 x 8 x 4 = 1024 blocks
    softhaus_pairwise<<<grid, BM, 0, stream>>>(pred, gt, row_sum, col_sum);
    softhaus_finalize<<<64, 256, 0, stream>>>(ws, (float*)d_out);
}

// Round 2
// 153.423 us; speedup vs baseline: 8.8473x; 8.8473x over previous
//
#include <hip/hip_runtime.h>

#define N_B   4
#define M_PTS 8192
#define K_PTS 8192
#define BM    256       // threads per block; each thread owns one "a" point
#define CHUNK 1024      // "b" points per block (K split across blockIdx.y)
#define KCH   (K_PTS / CHUNK)

// (ALPHA * log2(e))^2 : exp(-ALPHA*d) == exp2(-sqrt(s * C2)) with s = d^2
#define C2  52.0342243f
#define LN2 0.69314718055994531f

// out[a] += sum_b exp(-ALPHA * dist(A[a], B[b]))  over this block's b-chunk.
// blockIdx.z in [0, 2*N_B): first N_B -> A=pred,B=gt (row sums);
// second N_B -> A=gt,B=pred (col sums). Inner loop is pure VALU + scalar
// loads (uniform index) — no LDS, no DS atomics (R1 lesson: DS pipe was 93%).
__global__ __launch_bounds__(BM) void softhaus_sums(
    const float* __restrict__ pred, const float* __restrict__ gt,
    float* __restrict__ sums)
{
    const int  zb     = blockIdx.z;
    const bool second = zb >= N_B;
    const int  n      = second ? zb - N_B : zb;
    const float* Aset = second ? gt   : pred;
    const float* Bset = second ? pred : gt;
    float* out = sums + (second ? (size_t)N_B * M_PTS : 0);

    const int a = blockIdx.x * BM + threadIdx.x;
    const float2 p = ((const float2*)Aset)[(size_t)n * M_PTS + a];
    const float px = p.x, py = p.y;

    const float2* Bp = ((const float2*)Bset)
                     + (size_t)n * K_PTS + (size_t)blockIdx.y * CHUNK;

    float rs = 0.0f;
    #pragma unroll 8
    for (int j = 0; j < CHUNK; ++j) {
        const float2 g = Bp[j];              // block-uniform address -> s_load
        const float dx = px - g.x;
        const float dy = py - g.y;
        const float s  = fmaf(dy, dy, dx * dx) * C2;
        rs += __builtin_amdgcn_exp2f(-__builtin_amdgcn_sqrtf(s));
    }

    atomicAdd(&out[(size_t)n * M_PTS + a], rs);   // 8-way contention, coalesced
}

// ws holds row_sum (N*M) then col_sum (N*K).
// loss = mean(-log(row_sum)) + mean(-log(col_sum)); equal counts -> one scale.
__global__ __launch_bounds__(256) void softhaus_finalize(
    const float* __restrict__ sums, float* __restrict__ out)
{
    const int total  = N_B * M_PTS + N_B * K_PTS;
    const int idx    = blockIdx.x * blockDim.x + threadIdx.x;
    const int stride = gridDim.x * blockDim.x;

    float acc = 0.0f;
    for (int i = idx; i < total; i += stride)
        acc -= __builtin_amdgcn_logf(sums[i]) * LN2;   // -log(v)

    #pragma unroll
    for (int off = 32; off > 0; off >>= 1)
        acc += __shfl_down(acc, off);

    __shared__ float wsum[4];
    const int lane = threadIdx.x & 63;
    const int wv   = threadIdx.x >> 6;
    if (lane == 0) wsum[wv] = acc;
    __syncthreads();
    if (threadIdx.x == 0) {
        float b = wsum[0] + wsum[1] + wsum[2] + wsum[3];
        atomicAdd(out, b * (1.0f / (N_B * M_PTS)));
    }
}

extern "C" void kernel_launch(void* const* d_in, const int* in_sizes, int n_in,
                              void* d_out, int out_size, void* d_ws, size_t ws_size,
                              hipStream_t stream) {
    const float* pred = (const float*)d_in[0];
    const float* gt   = (const float*)d_in[1];
    float* ws = (float*)d_ws;

    const size_t acc_bytes = (size_t)(N_B * M_PTS + N_B * K_PTS) * sizeof(float);
    hipMemsetAsync(d_ws, 0, acc_bytes, stream);
    hipMemsetAsync(d_out, 0, sizeof(float), stream);

    dim3 grid(M_PTS / BM, KCH, 2 * N_B);   // 32 x 8 x 8 = 2048 blocks
    softhaus_sums<<<grid, BM, 0, stream>>>(pred, gt, ws);
    softhaus_finalize<<<64, 256, 0, stream>>>(ws, (float*)d_out);
}

// Round 3
// 85.736 us; speedup vs baseline: 15.8321x; 1.7895x over previous
//
#include <hip/hip_runtime.h>

#define N_B    4
#define M_PTS  8192
#define K_PTS  8192
#define RPL    4                 // rows per lane
#define BLK_ROWS (64 * RPL)      // 256 rows per block (all 4 waves share them)
#define WAVE_COLS 128            // columns per wave
#define BLK_COLS  (4 * WAVE_COLS)// 512 columns per block

// ALPHA * log2(e): pre-scale coords so exp(-ALPHA*d) == exp2(-sqrt(s'))
#define SCALE 7.21347520444481703f
#define LN2   0.69314718055994531f

typedef float v2f __attribute__((ext_vector_type(2)));

// one-lane wave rotate (DPP wave_ror:1 = 0x13C, gfx9/CDNA lineage).
__device__ __forceinline__ float ror1(float x) {
    int i = __float_as_int(x);
    return __int_as_float(__builtin_amdgcn_update_dpp(i, i, 0x13C, 0xF, 0xF, false));
}

// One pass over all pairs: row sums (pred side) in per-lane registers,
// column sums (gt side) in a traveling accumulator that rotates in sync
// with the per-lane gt point. Zero DS ops, zero cross-lane reductions in
// the inner loop (R1: DS atomics = 10x slowdown; R2: trans-issue-bound,
// so don't compute pairs twice).
__global__ __launch_bounds__(256) void softhaus_pair(
    const float* __restrict__ pred, const float* __restrict__ gt,
    float* __restrict__ row_sum, float* __restrict__ col_sum)
{
    const int n    = blockIdx.z;
    const int rb   = blockIdx.x * BLK_ROWS;
    const int tid  = threadIdx.x;
    const int lane = tid & 63;
    const int wv   = tid >> 6;

    const float2* P = (const float2*)pred + (size_t)n * M_PTS;
    const float2* G = (const float2*)gt   + (size_t)n * K_PTS;

    v2f   p[RPL];
    float rs[RPL];
    #pragma unroll
    for (int r = 0; r < RPL; ++r) {
        float2 t = P[rb + r * 64 + lane];
        p[r].x = t.x * SCALE; p[r].y = t.y * SCALE;
        rs[r] = 0.0f;
    }

    const int cbase = blockIdx.y * BLK_COLS + wv * WAVE_COLS;

    #pragma unroll
    for (int gset = 0; gset < WAVE_COLS / 64; ++gset) {
        const int c0 = cbase + gset * 64;
        float2 gg = G[c0 + lane];
        v2f g; g.x = gg.x * SCALE; g.y = gg.y * SCALE;
        float cacc = 0.0f;

        #pragma unroll 8
        for (int jj = 0; jj < 64; ++jj) {
            float e[RPL];
            #pragma unroll
            for (int r = 0; r < RPL; ++r) {
                v2f d = p[r] - g;        // v_pk_add_f32
                v2f q = d * d;           // v_pk_mul_f32
                float s = q.x + q.y;
                e[r] = __builtin_amdgcn_exp2f(-__builtin_amdgcn_sqrtf(s));
                rs[r] += e[r];
            }
            cacc += (e[0] + e[1]) + (e[2] + e[3]);
            // rotate gt point + its accumulator one lane (stay in sync);
            // 64 rotations total -> identity, cacc[lane] <-> column c0+lane
            g.x  = ror1(g.x);
            g.y  = ror1(g.y);
            cacc = ror1(cacc);
        }
        atomicAdd(&col_sum[(size_t)n * K_PTS + c0 + lane], cacc);
    }

    #pragma unroll
    for (int r = 0; r < RPL; ++r)
        atomicAdd(&row_sum[(size_t)n * M_PTS + rb + r * 64 + lane], rs[r]);
}

// ws: row_sum (N*M) then col_sum (N*K). Equal element counts -> single
// 1/(N*M) scale on the grand sum of -log terms.
__global__ __launch_bounds__(256) void softhaus_finalize(
    const float* __restrict__ sums, float* __restrict__ out)
{
    const int total  = N_B * M_PTS + N_B * K_PTS;
    const int idx    = blockIdx.x * blockDim.x + threadIdx.x;
    const int stride = gridDim.x * blockDim.x;

    float acc = 0.0f;
    for (int i = idx; i < total; i += stride)
        acc -= __builtin_amdgcn_logf(sums[i]) * LN2;   // -log(v)

    #pragma unroll
    for (int off = 32; off > 0; off >>= 1)
        acc += __shfl_down(acc, off);

    __shared__ float wsum[4];
    const int lane = threadIdx.x & 63;
    const int wv   = threadIdx.x >> 6;
    if (lane == 0) wsum[wv] = acc;
    __syncthreads();
    if (threadIdx.x == 0) {
        float b = wsum[0] + wsum[1] + wsum[2] + wsum[3];
        atomicAdd(out, b * (1.0f / (N_B * M_PTS)));
    }
}

extern "C" void kernel_launch(void* const* d_in, const int* in_sizes, int n_in,
                              void* d_out, int out_size, void* d_ws, size_t ws_size,
                              hipStream_t stream) {
    const float* pred = (const float*)d_in[0];
    const float* gt   = (const float*)d_in[1];
    float* ws = (float*)d_ws;

    const size_t acc_bytes = (size_t)(N_B * M_PTS + N_B * K_PTS) * sizeof(float);
    hipMemsetAsync(d_ws, 0, acc_bytes, stream);
    hipMemsetAsync(d_out, 0, sizeof(float), stream);

    dim3 grid(M_PTS / BLK_ROWS, K_PTS / BLK_COLS, N_B);  // 32 x 16 x 4 = 2048
    softhaus_pair<<<grid, 256, 0, stream>>>(pred, gt, ws, ws + (size_t)N_B * M_PTS);
    softhaus_finalize<<<64, 256, 0, stream>>>(ws, (float*)d_out);
}

// Round 4
// 84.708 us; speedup vs baseline: 16.0242x; 1.0121x over previous
//
#include <hip/hip_runtime.h>

#define N_B    4
#define M_PTS  8192
#define K_PTS  8192
#define RPL    8                  // rows per lane
#define BLK_ROWS  (64 * RPL)      // 512 rows per block (shared by 4 waves)
#define WAVE_COLS 64              // columns per wave
#define BLK_COLS  (4 * WAVE_COLS) // 256 columns per block

// coords pre-scaled by ALPHA*log2(e)*2^23 so sqrt(s') is directly the
// exponent-field delta for the Schraudolph exp2 bit-trick.
#define FS    (7.21347520444481703f * 8388608.0f)
// (127 - 0.0565)*2^23 : sigma tuned for ~zero MEAN relative error, so the
// +-3% ripple averages out across the 65536 softmin terms of the output mean.
#define EXPA  1064879260.0f
#define LN2   0.69314718055994531f

// one-lane whole-wave rotate (DPP wave_ror:1), proven in R3
__device__ __forceinline__ float ror1(float x) {
    int i = __float_as_int(x);
    return __int_as_float(__builtin_amdgcn_update_dpp(i, i, 0x13C, 0xF, 0xF, false));
}

// Single pass over all pairs. Row sums in per-lane registers; column sums in
// a traveling accumulator rotating in sync with the per-lane gt point.
// Inner loop per pair: sub,sub,mul,fma, v_sqrt(trans), sub, cvt, add
// = 7 full-rate + 1 trans. (R1: no DS ops; R2: no double pass; R3: exp2
// was ~12 trans cycles -> replaced by bit-trick.)
__global__ __launch_bounds__(256) void softhaus_pair(
    const float* __restrict__ pred, const float* __restrict__ gt,
    float* __restrict__ row_sum, float* __restrict__ col_sum)
{
    const int n    = blockIdx.z;
    const int rb   = blockIdx.x * BLK_ROWS;
    const int lane = threadIdx.x & 63;
    const int wv   = threadIdx.x >> 6;

    const float2* P = (const float2*)pred + (size_t)n * M_PTS;
    const float2* G = (const float2*)gt   + (size_t)n * K_PTS;

    float px[RPL], py[RPL], rs[RPL];
    #pragma unroll
    for (int r = 0; r < RPL; ++r) {
        float2 t = P[rb + r * 64 + lane];
        px[r] = t.x * FS;
        py[r] = t.y * FS;
        rs[r] = 0.0f;
    }

    const int c0 = blockIdx.y * BLK_COLS + wv * WAVE_COLS;
    float2 g0 = G[c0 + lane];
    float gx = g0.x * FS;
    float gy = g0.y * FS;
    float cacc = 0.0f;

    for (int jj = 0; jj < 64; ++jj) {
        float e[RPL];
        #pragma unroll
        for (int r = 0; r < RPL; ++r) {
            const float dx = px[r] - gx;
            const float dy = py[r] - gy;
            const float s  = fmaf(dx, dx, dy * dy);   // >= 0 exactly
            const float v  = __builtin_amdgcn_sqrtf(s);
            const float u  = EXPA - v;                // exp2 bit-trick
            e[r] = __int_as_float((int)u);
            rs[r] += e[r];
        }
        cacc += ((e[0] + e[1]) + (e[2] + e[3])) + ((e[4] + e[5]) + (e[6] + e[7]));
        // rotate gt point + its accumulator one lane; 64 rotations = identity
        gx   = ror1(gx);
        gy   = ror1(gy);
        cacc = ror1(cacc);
    }

    atomicAdd(&col_sum[(size_t)n * K_PTS + c0 + lane], cacc);  // 16 writers
    #pragma unroll
    for (int r = 0; r < RPL; ++r)                               // 32 writers
        atomicAdd(&row_sum[(size_t)n * M_PTS + rb + r * 64 + lane], rs[r]);
}

// ws: row_sum (N*M) then col_sum (N*K); equal counts -> single 1/(N*M) scale.
__global__ __launch_bounds__(256) void softhaus_finalize(
    const float* __restrict__ sums, float* __restrict__ out)
{
    const int total  = N_B * M_PTS + N_B * K_PTS;
    const int idx    = blockIdx.x * blockDim.x + threadIdx.x;
    const int stride = gridDim.x * blockDim.x;

    float acc = 0.0f;
    for (int i = idx; i < total; i += stride)
        acc -= __builtin_amdgcn_logf(sums[i]) * LN2;   // -log(v)

    #pragma unroll
    for (int off = 32; off > 0; off >>= 1)
        acc += __shfl_down(acc, off);

    __shared__ float wsum[4];
    const int lane = threadIdx.x & 63;
    const int wv   = threadIdx.x >> 6;
    if (lane == 0) wsum[wv] = acc;
    __syncthreads();
    if (threadIdx.x == 0) {
        float b = wsum[0] + wsum[1] + wsum[2] + wsum[3];
        atomicAdd(out, b * (1.0f / (N_B * M_PTS)));
    }
}

extern "C" void kernel_launch(void* const* d_in, const int* in_sizes, int n_in,
                              void* d_out, int out_size, void* d_ws, size_t ws_size,
                              hipStream_t stream) {
    const float* pred = (const float*)d_in[0];
    const float* gt   = (const float*)d_in[1];
    float* ws = (float*)d_ws;

    const size_t acc_bytes = (size_t)(N_B * M_PTS + N_B * K_PTS) * sizeof(float);
    hipMemsetAsync(d_ws, 0, acc_bytes, stream);
    hipMemsetAsync(d_out, 0, sizeof(float), stream);

    dim3 grid(M_PTS / BLK_ROWS, K_PTS / BLK_COLS, N_B);  // 16 x 32 x 4 = 2048
    softhaus_pair<<<grid, 256, 0, stream>>>(pred, gt, ws, ws + (size_t)N_B * M_PTS);
    softhaus_finalize<<<64, 256, 0, stream>>>(ws, (float*)d_out);
}

// Round 5
// 67.304 us; speedup vs baseline: 20.1679x; 1.2586x over previous
//
#include <hip/hip_runtime.h>

#define N_B    4
#define M_PTS  8192
#define K_PTS  8192
#define RPL    8                  // rows per lane (4 packed row-pairs)
#define BLK_ROWS  (64 * RPL)      // 512 rows per block (shared by 4 waves)
#define WAVE_COLS 64              // columns per wave
#define BLK_COLS  (4 * WAVE_COLS) // 256 columns per block

// coords pre-scaled by ALPHA*log2(e)*2^23 so sqrt(s') is directly the
// exponent-field delta for the Schraudolph exp2 bit-trick (validated R4).
#define FS    (7.21347520444481703f * 8388608.0f)
#define EXPA  1064879260.0f       // (127 - 0.0565)*2^23, zero-mean rel err
#define LN2   0.69314718055994531f

typedef float v2f __attribute__((ext_vector_type(2)));

// one-lane whole-wave rotate (DPP wave_ror:1), proven in R3/R4
__device__ __forceinline__ float ror1(float x) {
    int i = __float_as_int(x);
    return __int_as_float(__builtin_amdgcn_update_dpp(i, i, 0x13C, 0xF, 0xF, false));
}

// Single pass; row sums per-lane, column sums via traveling accumulator.
// R4 calibration: issue-bound at 2 cyc/full-rate, 11 cyc/trans. This round:
// pack row-pairs into v2f so the distance math runs on v_pk_* (VOP3P),
// halving the full-rate instruction stream. Per pair: ~4.5 full + 1 trans.
__global__ __launch_bounds__(256) void softhaus_pair(
    const float* __restrict__ pred, const float* __restrict__ gt,
    float* __restrict__ row_sum, float* __restrict__ col_sum)
{
    const int n    = blockIdx.z;
    const int rb   = blockIdx.x * BLK_ROWS;
    const int lane = threadIdx.x & 63;
    const int wv   = threadIdx.x >> 6;

    const float2* P = (const float2*)pred + (size_t)n * M_PTS;
    const float2* G = (const float2*)gt   + (size_t)n * K_PTS;

    v2f px2[RPL / 2], py2[RPL / 2], rs2[RPL / 2];
    #pragma unroll
    for (int i = 0; i < RPL / 2; ++i) {
        float2 a = P[rb + (2 * i    ) * 64 + lane];
        float2 b = P[rb + (2 * i + 1) * 64 + lane];
        px2[i].x = a.x * FS;  px2[i].y = b.x * FS;
        py2[i].x = a.y * FS;  py2[i].y = b.y * FS;
        rs2[i].x = 0.0f;      rs2[i].y = 0.0f;
    }

    const int c0 = blockIdx.y * BLK_COLS + wv * WAVE_COLS;
    float2 g0 = G[c0 + lane];
    float gx = g0.x * FS;
    float gy = g0.y * FS;
    float cacc = 0.0f;

    #pragma unroll 4
    for (int jj = 0; jj < 64; ++jj) {
        v2f gxx; gxx.x = gx; gxx.y = gx;
        v2f gyy; gyy.x = gy; gyy.y = gy;
        v2f e2[RPL / 2];
        #pragma unroll
        for (int i = 0; i < RPL / 2; ++i) {
            const v2f dx = px2[i] - gxx;          // v_pk_add (neg mod)
            const v2f dy = py2[i] - gyy;          // v_pk_add
            const v2f s  = dx * dx + dy * dy;     // v_pk_mul + v_pk_fma
            const float v0 = __builtin_amdgcn_sqrtf(s.x);   // trans
            const float v1 = __builtin_amdgcn_sqrtf(s.y);   // trans
            v2f e;
            e.x = __int_as_float((int)(EXPA - v0));  // sub+cvt (full rate)
            e.y = __int_as_float((int)(EXPA - v1));
            e2[i] = e;
            rs2[i] += e;                          // v_pk_add
        }
        const v2f t = (e2[0] + e2[1]) + (e2[2] + e2[3]);  // 3 pk adds
        cacc += t.x + t.y;
        // rotate gt point + its accumulator one lane; 64 rotations = identity
        gx   = ror1(gx);
        gy   = ror1(gy);
        cacc = ror1(cacc);
    }

    atomicAdd(&col_sum[(size_t)n * K_PTS + c0 + lane], cacc);   // 16 writers
    #pragma unroll
    for (int i = 0; i < RPL / 2; ++i) {                          // 32 writers
        atomicAdd(&row_sum[(size_t)n * M_PTS + rb + (2 * i    ) * 64 + lane], rs2[i].x);
        atomicAdd(&row_sum[(size_t)n * M_PTS + rb + (2 * i + 1) * 64 + lane], rs2[i].y);
    }
}

// ws: row_sum (N*M) then col_sum (N*K); equal counts -> single 1/(N*M) scale.
__global__ __launch_bounds__(256) void softhaus_finalize(
    const float* __restrict__ sums, float* __restrict__ out)
{
    const int total  = N_B * M_PTS + N_B * K_PTS;
    const int idx    = blockIdx.x * blockDim.x + threadIdx.x;
    const int stride = gridDim.x * blockDim.x;

    float acc = 0.0f;
    for (int i = idx; i < total; i += stride)
        acc -= __builtin_amdgcn_logf(sums[i]) * LN2;   // -log(v)

    #pragma unroll
    for (int off = 32; off > 0; off >>= 1)
        acc += __shfl_down(acc, off);

    __shared__ float wsum[4];
    const int lane = threadIdx.x & 63;
    const int wv   = threadIdx.x >> 6;
    if (lane == 0) wsum[wv] = acc;
    __syncthreads();
    if (threadIdx.x == 0) {
        float b = wsum[0] + wsum[1] + wsum[2] + wsum[3];
        atomicAdd(out, b * (1.0f / (N_B * M_PTS)));
    }
}

extern "C" void kernel_launch(void* const* d_in, const int* in_sizes, int n_in,
                              void* d_out, int out_size, void* d_ws, size_t ws_size,
                              hipStream_t stream) {
    const float* pred = (const float*)d_in[0];
    const float* gt   = (const float*)d_in[1];
    float* ws = (float*)d_ws;

    const size_t acc_bytes = (size_t)(N_B * M_PTS + N_B * K_PTS) * sizeof(float);
    hipMemsetAsync(d_ws, 0, acc_bytes, stream);
    hipMemsetAsync(d_out, 0, sizeof(float), stream);

    dim3 grid(M_PTS / BLK_ROWS, K_PTS / BLK_COLS, N_B);  // 16 x 32 x 4 = 2048
    softhaus_pair<<<grid, 256, 0, stream>>>(pred, gt, ws, ws + (size_t)N_B * M_PTS);
    softhaus_finalize<<<64, 256, 0, stream>>>(ws, (float*)d_out);
}